// Round 3
// baseline (370.731 us; speedup 1.0000x reference)
//
#include <hip/hip_runtime.h>

// Problem constants
#define Cn   192      // channels = 3*D
#define Dn   64       // hidden
#define G3   192      // 3*D gates
#define HWn  16384    // H*W per batch
#define NSp  131072L  // B*H*W total spatial
#define Tn   128

typedef unsigned short u16;
typedef __attribute__((ext_vector_type(8))) short s8v;   // 8 bf16 (4 VGPRs) MFMA A/B frag
typedef __attribute__((ext_vector_type(4))) float f4v;   // MFMA C/D frag

__device__ __forceinline__ float bf2f(u16 u){
  union { unsigned int i; float f; } v; v.i = ((unsigned int)u) << 16; return v.f;
}
__device__ __forceinline__ u16 f2bf(float f){
  union { float f; unsigned int u; } v; v.f = f;
  return (u16)((v.u + 0x7FFFu + ((v.u >> 16) & 1u)) >> 16);  // RNE
}
__device__ __forceinline__ s8v load8_f32_as_bf16(const float* __restrict__ p){
  s8v r;
  #pragma unroll
  for (int i = 0; i < 8; i++) r[i] = (short)f2bf(p[i]);
  return r;
}
__device__ __forceinline__ float sigf(float x){ return 1.f / (1.f + __expf(-x)); }
__device__ __forceinline__ float tanh_fast(float x){ return 2.f / (1.f + __expf(-2.f * x)) - 1.f; } // saturating

// lgkm-only barrier: does NOT drain outstanding global loads/stores (the
// __syncthreads vmcnt(0) drain was ~2000 cyc/step in round 2's k_scan).
__device__ __forceinline__ void barrier_lds_only(){
  asm volatile("s_waitcnt lgkmcnt(0)\n\ts_barrier" ::: "memory");
}

// ---------------------------------------------------------------------------
// Kernel 0: W_comb = W_ih @ Wi (bf16); b_comb = W_ih@bi + b_ih (+ b_hh for the
// r/z gates — those sums are linear so the recurrence bias folds into G).
// ---------------------------------------------------------------------------
__global__ __launch_bounds__(256) void k_wcomb(const float* __restrict__ Wi, const float* __restrict__ bi,
                                               const float* __restrict__ W_ih, const float* __restrict__ b_ih,
                                               const float* __restrict__ b_hh,
                                               u16* __restrict__ wcomb, float* __restrict__ bcomb){
  if (blockIdx.x < 144) {
    int idx = blockIdx.x * 256 + threadIdx.x;   // 36864 = 192*192
    int g = idx / 192, c = idx - g * 192;
    float acc = 0.f;
    #pragma unroll 8
    for (int d = 0; d < 64; d++)
      acc += W_ih[g * 64 + d] * Wi[d * 192 + c];
    wcomb[g * 192 + c] = f2bf(acc);
  } else if (threadIdx.x < 192) {
    int g = threadIdx.x;
    float acc = b_ih[g];
    for (int d = 0; d < 64; d++)
      acc += W_ih[g * 64 + d] * bi[d];
    if (g < 128) acc += b_hh[g];   // b_hh_n stays inside tanh's r*(...) — not foldable
    bcomb[g] = acc;
  }
}

// ---------------------------------------------------------------------------
// Kernel 1: G[s][g] = b_comb[g] + sum_c x[c][s] * W_comb[g][c]   (bf16 out)
// MFMA M=64/N=192/K=192; B-frags in regs; A via LDS transpose; epilogue
// repacks C through LDS (reusing xT) for fully-coalesced 16B stores.
// ---------------------------------------------------------------------------
__global__ __launch_bounds__(256) void k_gates(const float* __restrict__ x, const u16* __restrict__ wcomb,
                                               const float* __restrict__ bcomb, u16* __restrict__ G){
  __shared__ u16 xT[64][200];                 // [spatial][channel], row 400 B (16B-aligned)
  const int tid = threadIdx.x;
  const int wave = tid >> 6, lane = tid & 63;
  const int col = lane & 15, kq = lane >> 4;
  const long s0 = (long)blockIdx.x * 64;
  const int b   = (int)(s0 >> 14);
  const int hw0 = (int)(s0 & 16383);

  // B-fragments: wave handles gates [48w, 48w+48): 3 n-tiles x 6 k-chunks
  s8v bfrag[3][6];
  #pragma unroll
  for (int j = 0; j < 3; j++) {
    int g = wave * 48 + j * 16 + col;
    #pragma unroll
    for (int kc = 0; kc < 6; kc++)
      bfrag[j][kc] = *(const s8v*)(wcomb + g * 192 + kc * 32 + kq * 8);
  }

  // Stage x tile transposed: float4 (4 consecutive spatial), cvt bf16
  for (int idx = tid; idx < 192 * 16; idx += 256) {
    int c  = idx >> 4;
    int s4 = (idx & 15) * 4;
    float4 v = *(const float4*)(x + (long)(b * 192 + c) * HWn + hw0 + s4);
    xT[s4 + 0][c] = f2bf(v.x); xT[s4 + 1][c] = f2bf(v.y);
    xT[s4 + 2][c] = f2bf(v.z); xT[s4 + 3][c] = f2bf(v.w);
  }
  __syncthreads();

  f4v acc[4][3];
  #pragma unroll
  for (int m = 0; m < 4; m++)
    #pragma unroll
    for (int j = 0; j < 3; j++) acc[m][j] = (f4v){0.f, 0.f, 0.f, 0.f};

  #pragma unroll
  for (int kc = 0; kc < 6; kc++) {
    #pragma unroll
    for (int m = 0; m < 4; m++) {
      s8v a = *(const s8v*)(&xT[m * 16 + col][kc * 32 + kq * 8]);
      #pragma unroll
      for (int j = 0; j < 3; j++)
        acc[m][j] = __builtin_amdgcn_mfma_f32_16x16x32_bf16(a, bfrag[j][kc], acc[m][j], 0, 0, 0);
    }
  }
  __syncthreads();   // all xT reads done; reuse xT for output repack

  #pragma unroll
  for (int j = 0; j < 3; j++) {
    int g = wave * 48 + j * 16 + col;
    float bias = bcomb[g];
    #pragma unroll
    for (int m = 0; m < 4; m++)
      #pragma unroll
      for (int r = 0; r < 4; r++)
        xT[m * 16 + kq * 4 + r][g] = f2bf(acc[m][j][r] + bias);
  }
  __syncthreads();

  // coalesced store: 64 rows x 384 B contiguous
  for (int c = tid; c < 64 * 24; c += 256) {
    int sp = c / 24, q = c - sp * 24;
    ulonglong2 v = *(const ulonglong2*)(&xT[sp][q * 8]);
    *(ulonglong2*)(G + (s0 + sp) * 192 + q * 8) = v;
  }
}

// ---------------------------------------------------------------------------
// Kernel 2: directional GRU scans. Block = 16 sequences of one direction,
// 4 waves. Wave w owns n-tiles {w, 4+w, 8+w} => the r/z/n gate triplet for
// d in [16w,16w+16) stays in ONE lane's C registers — no HG LDS round-trip.
// xr/xz enter via MFMA C-init (biases pre-folded into G); b_hh_n via C-init
// of the n accumulator. Only h crosses waves (double-buffered LDS, one
// lgkm-only barrier per step; global G-prefetch/h-store never drained).
// ---------------------------------------------------------------------------
__global__ __launch_bounds__(256) void k_scan(const u16* __restrict__ G, const float* __restrict__ W_hh,
                                              const float* __restrict__ b_hh, u16* __restrict__ Hall){
  __shared__ u16 ha[2][16][72];    // h bf16, A-frag layout [seq][d], row 144 B
  const int tid = threadIdx.x;
  const int wave = tid >> 6, lane = tid & 63;
  const int col = lane & 15, kq = lane >> 4;
  const int dcol = wave * 16 + col;           // this wave's d index
  const int dir  = blockIdx.x >> 6;           // 0:right 1:down 2:left 3:up
  const int sblk = blockIdx.x & 63;

  // persistent W_hh B-frags: tau in {r,z,n} -> gate row g = tau*64 + dcol
  s8v bfrag[3][2];
  #pragma unroll
  for (int tau = 0; tau < 3; tau++) {
    int g = tau * 64 + dcol;
    bfrag[tau][0] = load8_f32_as_bf16(W_hh + g * 64 + kq * 8);
    bfrag[tau][1] = load8_f32_as_bf16(W_hh + g * 64 + 32 + kq * 8);
  }
  const float bn = b_hh[128 + dcol];
  const f4v biasn = {bn, bn, bn, bn};

  // 4 sequences per lane: seq slot = kq*4 + r
  int baseo[4];
  #pragma unroll
  for (int r = 0; r < 4; r++) {
    int gseq = sblk * 16 + kq * 4 + r;
    int b = gseq >> 7, a = gseq & 127;
    baseo[r] = ((dir & 1) == 0) ? (b * 128 + a) * 128 : b * 16384 + a;
  }
  const int stride = ((dir & 1) == 0) ? 1 : 128;
  const int rev = dir >> 1;
  u16* __restrict__ Hs = Hall + (long)dir * (NSp * 64);

  for (int i = tid; i < 2 * 16 * 72; i += 256) ((u16*)ha)[i] = 0;  // h0 = 0 (both buffers)

  // 2-deep xg prefetch: [tau*4 + r]
  u16 xg[2][12];
  #pragma unroll
  for (int pf = 0; pf < 2; pf++) {
    int tp = rev ? 127 - pf : pf;
    #pragma unroll
    for (int r = 0; r < 4; r++) {
      const u16* gp = G + (long)(baseo[r] + tp * stride) * 192 + dcol;
      xg[pf][0 + r] = gp[0];
      xg[pf][4 + r] = gp[64];
      xg[pf][8 + r] = gp[128];
    }
  }
  float hold[4] = {0.f, 0.f, 0.f, 0.f};
  barrier_lds_only();

  #pragma unroll 2
  for (int t = 0; t < 128; t++) {
    const int cur = t & 1;
    // A-frags of h(t-1) from buffer written last step
    s8v a0 = *(const s8v*)(&ha[cur][col][kq * 8]);
    s8v a1 = *(const s8v*)(&ha[cur][col][32 + kq * 8]);

    // consume this step's xg, then reuse its regs for the t+2 prefetch
    float xf[12];
    #pragma unroll
    for (int i = 0; i < 12; i++) xf[i] = bf2f(xg[cur][i]);
    if (t < 126) {
      int tp = rev ? 125 - t : t + 2;
      #pragma unroll
      for (int r = 0; r < 4; r++) {
        const u16* gp = G + (long)(baseo[r] + tp * stride) * 192 + dcol;
        xg[cur][0 + r] = gp[0];
        xg[cur][4 + r] = gp[64];
        xg[cur][8 + r] = gp[128];
      }
    }

    // HG = h @ W_hh^T, with xr/xz (all biases folded) and b_hh_n as C-init
    f4v accR = {xf[0], xf[1], xf[2], xf[3]};
    f4v accZ = {xf[4], xf[5], xf[6], xf[7]};
    f4v accN = biasn;
    accR = __builtin_amdgcn_mfma_f32_16x16x32_bf16(a0, bfrag[0][0], accR, 0, 0, 0);
    accR = __builtin_amdgcn_mfma_f32_16x16x32_bf16(a1, bfrag[0][1], accR, 0, 0, 0);
    accZ = __builtin_amdgcn_mfma_f32_16x16x32_bf16(a0, bfrag[1][0], accZ, 0, 0, 0);
    accZ = __builtin_amdgcn_mfma_f32_16x16x32_bf16(a1, bfrag[1][1], accZ, 0, 0, 0);
    accN = __builtin_amdgcn_mfma_f32_16x16x32_bf16(a0, bfrag[2][0], accN, 0, 0, 0);
    accN = __builtin_amdgcn_mfma_f32_16x16x32_bf16(a1, bfrag[2][1], accN, 0, 0, 0);

    // gate phase: everything for (seq=kq*4+r, d=dcol) is in-register
    const int tpos = rev ? 127 - t : t;
    #pragma unroll
    for (int r = 0; r < 4; r++) {
      float rr = sigf(accR[r]);
      float zz = sigf(accZ[r]);
      float nn = tanh_fast(xf[8 + r] + rr * accN[r]);
      float h  = nn + zz * (hold[r] - nn);
      hold[r] = h;
      u16 hb = f2bf(h);
      ha[cur ^ 1][kq * 4 + r][dcol] = hb;                       // h(t) for next step
      Hs[(long)(baseo[r] + tpos * stride) * 64 + dcol] = hb;    // stream out (never drained)
    }
    barrier_lds_only();
  }
}

// ---------------------------------------------------------------------------
// Kernel 3: out[b,c,h,w] = bo[c] + Wo[c,:] . (sum_dirs h)/4   (fp32 out)
// ---------------------------------------------------------------------------
__global__ __launch_bounds__(256) void k_out(const u16* __restrict__ Hall, const float* __restrict__ Wo,
                                             const float* __restrict__ bo, float* __restrict__ out){
  __shared__ u16 hs4[64][72];
  const int tid = threadIdx.x;
  const int wave = tid >> 6, lane = tid & 63;
  const int col = lane & 15, kq = lane >> 4;
  const long s0 = (long)blockIdx.x * 64;
  const int b   = (int)(s0 >> 14);
  const int hw0 = (int)(s0 & 16383);

  s8v bfrag[3][2]; f4v biasf[3];
  #pragma unroll
  for (int j = 0; j < 3; j++) {
    int g = wave * 48 + j * 16 + col;
    bfrag[j][0] = load8_f32_as_bf16(Wo + g * 64 + kq * 8);
    bfrag[j][1] = load8_f32_as_bf16(Wo + g * 64 + 32 + kq * 8);
    float bb = bo[g];
    biasf[j] = (f4v){bb, bb, bb, bb};
  }

  // Stage (sum of 4 direction h)/4 as bf16
  for (int idx = tid; idx < 64 * 16; idx += 256) {
    int sl = idx >> 4;
    int d4 = (idx & 15) * 4;
    long p = (s0 + sl) * 64 + d4;
    float a0 = 0.f, a1 = 0.f, a2 = 0.f, a3 = 0.f;
    #pragma unroll
    for (int dd = 0; dd < 4; dd++) {
      uint2 v = *(const uint2*)(Hall + dd * (NSp * 64) + p);
      u16* pv = (u16*)&v;
      a0 += bf2f(pv[0]); a1 += bf2f(pv[1]); a2 += bf2f(pv[2]); a3 += bf2f(pv[3]);
    }
    ushort4 o;
    o.x = f2bf(0.25f * a0); o.y = f2bf(0.25f * a1);
    o.z = f2bf(0.25f * a2); o.w = f2bf(0.25f * a3);
    *(ushort4*)(&hs4[sl][d4]) = o;
  }
  __syncthreads();

  f4v acc[4][3];
  #pragma unroll
  for (int m = 0; m < 4; m++)
    #pragma unroll
    for (int j = 0; j < 3; j++) acc[m][j] = biasf[j];

  #pragma unroll
  for (int kc = 0; kc < 2; kc++) {
    #pragma unroll
    for (int m = 0; m < 4; m++) {
      s8v a = *(const s8v*)(&hs4[m * 16 + col][kc * 32 + kq * 8]);
      #pragma unroll
      for (int j = 0; j < 3; j++)
        acc[m][j] = __builtin_amdgcn_mfma_f32_16x16x32_bf16(a, bfrag[j][kc], acc[m][j], 0, 0, 0);
    }
  }

  #pragma unroll
  for (int j = 0; j < 3; j++) {
    int g = wave * 48 + j * 16 + col;
    #pragma unroll
    for (int m = 0; m < 4; m++) {
      float4 v;
      v.x = acc[m][j][0]; v.y = acc[m][j][1];
      v.z = acc[m][j][2]; v.w = acc[m][j][3];
      long addr = ((long)(b * 192 + g) << 14) + hw0 + m * 16 + kq * 4;
      *(float4*)(out + addr) = v;
    }
  }
}

// ---------------------------------------------------------------------------
extern "C" void kernel_launch(void* const* d_in, const int* in_sizes, int n_in,
                              void* d_out, int out_size, void* d_ws, size_t ws_size,
                              hipStream_t stream){
  const float* x    = (const float*)d_in[0];
  const float* Wi   = (const float*)d_in[1];
  const float* bi   = (const float*)d_in[2];
  const float* W_ih = (const float*)d_in[3];
  const float* W_hh = (const float*)d_in[4];
  const float* b_ih = (const float*)d_in[5];
  const float* b_hh = (const float*)d_in[6];
  const float* Wo   = (const float*)d_in[7];
  const float* bo   = (const float*)d_in[8];

  char* ws = (char*)d_ws;
  u16*   wcomb = (u16*)(ws);                       // 192*192 bf16        = 73728 B
  float* bcomb = (float*)(ws + 73728);             // 192 fp32            = 768 B
  u16*   G     = (u16*)(ws + 74496);               // 131072*192 bf16     = 50331648 B
  u16*   Hall  = (u16*)(ws + 50406144);            // 4*131072*64 bf16    = 67108864 B
                                                   // total               = 117515008 B

  k_wcomb<<<145,  256, 0, stream>>>(Wi, bi, W_ih, b_ih, b_hh, wcomb, bcomb);
  k_gates<<<2048, 256, 0, stream>>>(x, wcomb, bcomb, G);
  k_scan <<<256,  256, 0, stream>>>(G, W_hh, b_hh, Hall);
  k_out  <<<2048, 256, 0, stream>>>(Hall, Wo, bo, (float*)d_out);
}